// Round 1
// baseline (3672.961 us; speedup 1.0000x reference)
//
#include <hip/hip_runtime.h>

#define NN 50000
#define NE 800000
#define IND 128
#define NH 8
#define DH 16
#define NR 9

// W[r,i,o] = sum_b comb[r,b] * basis[b,i,o]
__global__ __launch_bounds__(256) void combine_w(const float* __restrict__ basis,
                                                 const float* __restrict__ comb,
                                                 float* __restrict__ W) {
  int idx = blockIdx.x * 256 + threadIdx.x;   // 0..IND*IND-1 (16384, exact)
  int r = blockIdx.y;
  float acc = 0.f;
#pragma unroll
  for (int b = 0; b < NR; ++b)
    acc += comb[r * NR + b] * basis[(long)b * IND * IND + idx];
  W[(long)r * IND * IND + idx] = acc;
}

// A[(r-rlo), dst, :] += x[src, :]   (32 lanes per edge, float4 each)
__global__ __launch_bounds__(256) void scatter_x(const float* __restrict__ x,
                                                 const int* __restrict__ src,
                                                 const int* __restrict__ dst,
                                                 const int* __restrict__ et,
                                                 float* __restrict__ A,
                                                 int rlo, int rhi) {
  long tid = (long)blockIdx.x * 256 + threadIdx.x;
  int e = (int)(tid >> 5);
  int lane = (int)(tid & 31);
  if (e >= NE) return;
  int r = et[e];
  if (r < rlo || r >= rhi) return;
  const float4 xv = *(const float4*)(x + (long)src[e] * IND + lane * 4);
  float* a = A + ((long)(r - rlo) * NN + dst[e]) * IND + lane * 4;
  atomicAdd(a + 0, xv.x);
  atomicAdd(a + 1, xv.y);
  atomicAdd(a + 2, xv.z);
  atomicAdd(a + 3, xv.w);
}

// Fused 3-output GEMM: F[m][n,o] (+)= sum_{r,i} A[r,n,i] * W3[m, rlo+r, i, o]
// Block: 256 threads, 64-row tile, full 128 output cols, 3 matrices.
__global__ __launch_bounds__(256) void gemm3(const float* __restrict__ A,
                                             const float* __restrict__ W3,
                                             float* __restrict__ F,
                                             int nrel, int rlo, int first) {
  __shared__ float Al[16][68];          // [i_local][n_local], padded/aligned
  __shared__ float Wl[3][16][IND];      // 24 KB

  const int t = threadIdx.x;
  const int tx = t & 15;                // o-group
  const int ty = t >> 4;                // n-group (4 rows each)
  const int n0 = blockIdx.x * 64;

  float acc[3][4][8];
#pragma unroll
  for (int m = 0; m < 3; ++m)
#pragma unroll
    for (int j = 0; j < 4; ++j)
#pragma unroll
      for (int c = 0; c < 8; ++c) acc[m][j][c] = 0.f;

  for (int r = 0; r < nrel; ++r) {
    const float* Ar = A + ((long)r * NN + n0) * IND;
    const long wbase = ((long)rlo + r) * IND * IND;
    for (int it = 0; it < IND; it += 16) {
      __syncthreads();
      // stage A tile (transposed): thread loads float4 at (row=t>>2, col=it+(t&3)*4)
      {
        int row = t >> 2, col = (t & 3) * 4;
        float4 av = make_float4(0.f, 0.f, 0.f, 0.f);
        if (n0 + row < NN) av = *(const float4*)(Ar + (long)row * IND + it + col);
        Al[col + 0][row] = av.x;
        Al[col + 1][row] = av.y;
        Al[col + 2][row] = av.z;
        Al[col + 3][row] = av.w;
      }
      // stage W tiles for the 3 matrices
#pragma unroll
      for (int m = 0; m < 3; ++m) {
        const float* Wr = W3 + (long)m * NR * IND * IND + wbase + (long)it * IND;
#pragma unroll
        for (int k = 0; k < 2; ++k) {
          int f = t + k * 256;          // float4 index, 0..511
          int rr = f >> 5;              // 0..15
          int cc = (f & 31) * 4;        // 0..124
          *(float4*)&Wl[m][rr][cc] = *(const float4*)(Wr + (long)rr * IND + cc);
        }
      }
      __syncthreads();
#pragma unroll
      for (int i = 0; i < 16; ++i) {
        float av[4];
        *(float4*)&av[0] = *(const float4*)&Al[i][ty * 4];
#pragma unroll
        for (int m = 0; m < 3; ++m) {
          float w[8];
          *(float4*)&w[0] = *(const float4*)&Wl[m][i][tx * 4];
          *(float4*)&w[4] = *(const float4*)&Wl[m][i][64 + tx * 4];
#pragma unroll
          for (int j = 0; j < 4; ++j)
#pragma unroll
            for (int c = 0; c < 8; ++c) acc[m][j][c] += av[j] * w[c];
        }
      }
    }
  }

  // epilogue
#pragma unroll
  for (int m = 0; m < 3; ++m) {
    float* Fm = F + (long)m * NN * IND;
#pragma unroll
    for (int j = 0; j < 4; ++j) {
      int n = n0 + ty * 4 + j;
      if (n >= NN) continue;
      float* p0 = Fm + (long)n * IND + tx * 4;
      float4 v0 = make_float4(acc[m][j][0], acc[m][j][1], acc[m][j][2], acc[m][j][3]);
      float4 v1 = make_float4(acc[m][j][4], acc[m][j][5], acc[m][j][6], acc[m][j][7]);
      if (first) {
        *(float4*)p0 = v0;
        *(float4*)(p0 + 64) = v1;
      } else {
        float4 o0 = *(float4*)p0, o1 = *(float4*)(p0 + 64);
        o0.x += v0.x; o0.y += v0.y; o0.z += v0.z; o0.w += v0.w;
        o1.x += v1.x; o1.y += v1.y; o1.z += v1.z; o1.w += v1.w;
        *(float4*)p0 = o0;
        *(float4*)(p0 + 64) = o1;
      }
    }
  }
}

__global__ __launch_bounds__(256) void bias_relu(float* __restrict__ F,
                                                 const float* __restrict__ qb,
                                                 const float* __restrict__ kb,
                                                 const float* __restrict__ vb) {
  int m = blockIdx.y;
  const float* b = (m == 0) ? qb : (m == 1) ? kb : vb;
  long idx = (long)blockIdx.x * 256 + threadIdx.x;
  if (idx >= (long)NN * IND) return;
  float* Fm = F + (long)m * NN * IND;
  float v = Fm[idx] + b[idx & (IND - 1)];
  Fm[idx] = v > 0.f ? v : 0.f;
}

// 32 lanes per edge: per-head QK dot (shfl reduce over 4 lanes), exp-clip,
// atomic wV into out and score sum into z.
__global__ __launch_bounds__(256) void edge_attn(const float* __restrict__ Q,
                                                 const float* __restrict__ K,
                                                 const float* __restrict__ V,
                                                 const int* __restrict__ src,
                                                 const int* __restrict__ dst,
                                                 float* __restrict__ out,
                                                 float* __restrict__ z) {
  long tid = (long)blockIdx.x * 256 + threadIdx.x;
  int e = (int)(tid >> 5);
  int lane = (int)(tid & 31);
  if (e >= NE) return;
  int s = src[e], d = dst[e];
  int off = (lane >> 2) * DH + (lane & 3) * 4;  // head*16 + chunk*4
  float4 q = *(const float4*)(Q + (long)d * IND + off);
  float4 k = *(const float4*)(K + (long)s * IND + off);
  float p = q.x * k.x + q.y * k.y + q.z * k.z + q.w * k.w;
  p += __shfl_xor(p, 1);
  p += __shfl_xor(p, 2);
  float score = expf(fminf(fmaxf(p * 0.25f, -10.f), 10.f));
  float4 v = *(const float4*)(V + (long)s * IND + off);
  float* o = out + (long)d * IND + off;
  atomicAdd(o + 0, v.x * score);
  atomicAdd(o + 1, v.y * score);
  atomicAdd(o + 2, v.z * score);
  atomicAdd(o + 3, v.w * score);
  if ((lane & 3) == 0) atomicAdd(z + (long)d * NH + (lane >> 2), score);
}

__global__ __launch_bounds__(256) void finalize(float* __restrict__ out,
                                                const float* __restrict__ z) {
  long idx = (long)blockIdx.x * 256 + threadIdx.x;
  if (idx >= (long)NN * IND) return;
  int n = (int)(idx >> 7);
  int h = (int)((idx >> 4) & 7);
  out[idx] = out[idx] / (z[n * NH + h] + 1e-6f);
}

extern "C" void kernel_launch(void* const* d_in, const int* in_sizes, int n_in,
                              void* d_out, int out_size, void* d_ws, size_t ws_size,
                              hipStream_t stream) {
  const float* h  = (const float*)d_in[0];
  const float* Qw = (const float*)d_in[1];
  const float* Qc = (const float*)d_in[2];
  const float* Qb = (const float*)d_in[3];
  const float* Kw = (const float*)d_in[4];
  const float* Kc = (const float*)d_in[5];
  const float* Kb = (const float*)d_in[6];
  const float* Vw = (const float*)d_in[7];
  const float* Vc = (const float*)d_in[8];
  const float* Vb = (const float*)d_in[9];
  const int* src = (const int*)d_in[10];
  const int* dst = (const int*)d_in[11];
  const int* et  = (const int*)d_in[12];
  float* out = (float*)d_out;
  float* ws = (float*)d_ws;

  const long WSZ = (long)NR * IND * IND;      // 147456 floats per weight set
  float* W3 = ws;                              // [3][R][IN][IN]
  float* F  = W3 + 3 * WSZ;                    // [3][N][IN]
  float* z  = F + 3L * NN * IND;               // [N][H]
  float* A  = z + (long)NN * NH;               // [C][N][IN]

  long fixedf = 3 * WSZ + 3L * NN * IND + (long)NN * NH;
  long availf = (long)(ws_size / 4) - fixedf;
  long per_rel = (long)NN * IND;
  int C = (int)(availf / per_rel);
  if (C > NR) C = NR;
  if (C < 1) C = 1;  // nothing better available

  hipMemsetAsync(z, 0, (size_t)NN * NH * 4, stream);
  hipMemsetAsync(out, 0, (size_t)NN * IND * 4, stream);

  combine_w<<<dim3(64, NR), 256, 0, stream>>>(Qw, Qc, W3);
  combine_w<<<dim3(64, NR), 256, 0, stream>>>(Kw, Kc, W3 + WSZ);
  combine_w<<<dim3(64, NR), 256, 0, stream>>>(Vw, Vc, W3 + 2 * WSZ);

  const int scatter_blocks = (int)(((long)NE * 32 + 255) / 256);  // 100000
  const int gemm_blocks = (NN + 63) / 64;                          // 782

  int first = 1;
  for (int rlo = 0; rlo < NR; rlo += C) {
    int rhi = rlo + C;
    if (rhi > NR) rhi = NR;
    int nr = rhi - rlo;
    hipMemsetAsync(A, 0, (size_t)nr * NN * IND * 4, stream);
    scatter_x<<<scatter_blocks, 256, 0, stream>>>(h, src, dst, et, A, rlo, rhi);
    gemm3<<<gemm_blocks, 256, 0, stream>>>(A, W3, F, nr, rlo, first);
    first = 0;
  }

  bias_relu<<<dim3((int)(((long)NN * IND + 255) / 256), 3), 256, 0, stream>>>(F, Qb, Kb, Vb);

  edge_attn<<<scatter_blocks, 256, 0, stream>>>(F, F + (long)NN * IND, F + 2L * NN * IND,
                                                src, dst, out, z);
  finalize<<<(int)(((long)NN * IND + 255) / 256), 256, 0, stream>>>(out, z);
}

// Round 2
// 1157.352 us; speedup vs baseline: 3.1736x; 3.1736x over previous
//
#include <hip/hip_runtime.h>

#define NN 50000
#define NE 800000
#define IND 128
#define NH 8
#define DH 16
#define NR 9
#define NBLK 196   // ceil(NN/256)

// ---------------- weight combine: W[r,i,o] = sum_b comb[r,b]*basis[b,i,o] ----
__global__ __launch_bounds__(256) void combine_w(const float* __restrict__ basis,
                                                 const float* __restrict__ comb,
                                                 float* __restrict__ W) {
  int idx = blockIdx.x * 256 + threadIdx.x;   // 0..IND*IND-1
  int r = blockIdx.y;
  float acc = 0.f;
#pragma unroll
  for (int b = 0; b < NR; ++b)
    acc += comb[r * NR + b] * basis[(long)b * IND * IND + idx];
  W[(long)r * IND * IND + idx] = acc;
}

// ---------------- CSR build -------------------------------------------------
__global__ __launch_bounds__(256) void hist_dst(const int* __restrict__ dst,
                                                int* __restrict__ deg) {
  int e = blockIdx.x * 256 + threadIdx.x;
  if (e < NE) atomicAdd(&deg[dst[e]], 1);
}

__global__ __launch_bounds__(256) void scan_p1(const int* __restrict__ deg,
                                               int* __restrict__ bsum) {
  __shared__ int sb[256];
  int t = threadIdx.x;
  int idx = blockIdx.x * 256 + t;
  int v = (idx < NN) ? deg[idx] : 0;
  sb[t] = v;
  __syncthreads();
  for (int off = 128; off > 0; off >>= 1) {
    if (t < off) sb[t] += sb[t + off];
    __syncthreads();
  }
  if (t == 0) bsum[blockIdx.x] = sb[0];
}

__global__ __launch_bounds__(256) void scan_p2(const int* __restrict__ bsum,
                                               int* __restrict__ boff,
                                               int* __restrict__ rowptr) {
  __shared__ int sb[256];
  int t = threadIdx.x;
  int v = (t < NBLK) ? bsum[t] : 0;
  sb[t] = v;
  __syncthreads();
  for (int off = 1; off < 256; off <<= 1) {
    int add = (t >= off) ? sb[t - off] : 0;
    __syncthreads();
    sb[t] += add;
    __syncthreads();
  }
  if (t < NBLK) boff[t] = sb[t] - v;   // exclusive
  if (t == 0) rowptr[NN] = NE;
}

__global__ __launch_bounds__(256) void scan_p3(const int* __restrict__ deg,
                                               const int* __restrict__ boff,
                                               int* __restrict__ rowptr,
                                               int* __restrict__ cursor) {
  __shared__ int sb[256];
  int t = threadIdx.x;
  int idx = blockIdx.x * 256 + t;
  int v = (idx < NN) ? deg[idx] : 0;
  sb[t] = v;
  __syncthreads();
  for (int off = 1; off < 256; off <<= 1) {
    int add = (t >= off) ? sb[t - off] : 0;
    __syncthreads();
    sb[t] += add;
    __syncthreads();
  }
  if (idx < NN) {
    int excl = sb[t] - v + boff[blockIdx.x];
    rowptr[idx] = excl;
    cursor[idx] = excl;
  }
}

__global__ __launch_bounds__(256) void bucket_edges(const int* __restrict__ src,
                                                    const int* __restrict__ dst,
                                                    const int* __restrict__ et,
                                                    int* __restrict__ cursor,
                                                    int* __restrict__ epk) {
  int e = blockIdx.x * 256 + threadIdx.x;
  if (e >= NE) return;
  int d = dst[e];
  int pos = atomicAdd(&cursor[d], 1);
  epk[pos] = src[e] | (et[e] << 20);   // src < 2^17, et < 16
}

// ---------------- per-node relational aggregation (no atomics) --------------
// wave per node: acc[r][2] in regs, write A[r - rlo][n][:]
__global__ __launch_bounds__(256) void conv_agg(const float* __restrict__ x,
                                                const int* __restrict__ rowptr,
                                                const int* __restrict__ epk,
                                                float* __restrict__ A,
                                                int rlo, int rhi) {
  int wid = (blockIdx.x * 256 + threadIdx.x) >> 6;
  int lane = threadIdx.x & 63;
  if (wid >= NN) return;
  float ax[NR], ay[NR];
#pragma unroll
  for (int rr = 0; rr < NR; ++rr) { ax[rr] = 0.f; ay[rr] = 0.f; }
  int r0 = rowptr[wid], r1 = rowptr[wid + 1];
  for (int base = r0; base < r1; base += 64) {
    int pe = (base + lane < r1) ? epk[base + lane] : 0;
    int cnt = min(64, r1 - base);
    for (int j = 0; j < cnt; ++j) {
      int p = __shfl(pe, j);
      int s = p & 0xFFFFF;
      int r = p >> 20;
      float2 xv = *(const float2*)(x + (long)s * IND + lane * 2);
#pragma unroll
      for (int rr = 0; rr < NR; ++rr)
        if (r == rr) { ax[rr] += xv.x; ay[rr] += xv.y; }
    }
  }
#pragma unroll
  for (int rr = 0; rr < NR; ++rr)
    if (rr >= rlo && rr < rhi) {
      float* a = A + ((long)(rr - rlo) * NN + wid) * IND + lane * 2;
      *(float2*)a = make_float2(ax[rr], ay[rr]);
    }
}

// ---------------- fused 3-output GEMM + bias + relu -------------------------
__global__ __launch_bounds__(256) void gemm3(const float* __restrict__ A,
                                             const float* __restrict__ W3,
                                             float* __restrict__ F,
                                             const float* __restrict__ qb,
                                             const float* __restrict__ kb,
                                             const float* __restrict__ vb,
                                             int nrel, int rlo, int first, int last) {
  __shared__ float Al[16][68];
  __shared__ float Wl[3][16][IND];

  const int t = threadIdx.x;
  const int tx = t & 15;
  const int ty = t >> 4;
  const int n0 = blockIdx.x * 64;

  float acc[3][4][8];
#pragma unroll
  for (int m = 0; m < 3; ++m)
#pragma unroll
    for (int j = 0; j < 4; ++j)
#pragma unroll
      for (int c = 0; c < 8; ++c) acc[m][j][c] = 0.f;

  for (int r = 0; r < nrel; ++r) {
    const float* Ar = A + ((long)r * NN + n0) * IND;
    const long wbase = ((long)rlo + r) * IND * IND;
    for (int it = 0; it < IND; it += 16) {
      __syncthreads();
      {
        int row = t >> 2, col = (t & 3) * 4;
        float4 av = make_float4(0.f, 0.f, 0.f, 0.f);
        if (n0 + row < NN) av = *(const float4*)(Ar + (long)row * IND + it + col);
        Al[col + 0][row] = av.x;
        Al[col + 1][row] = av.y;
        Al[col + 2][row] = av.z;
        Al[col + 3][row] = av.w;
      }
#pragma unroll
      for (int m = 0; m < 3; ++m) {
        const float* Wr = W3 + (long)m * NR * IND * IND + wbase + (long)it * IND;
#pragma unroll
        for (int k = 0; k < 2; ++k) {
          int f = t + k * 256;
          int rr = f >> 5;
          int cc = (f & 31) * 4;
          *(float4*)&Wl[m][rr][cc] = *(const float4*)(Wr + (long)rr * IND + cc);
        }
      }
      __syncthreads();
#pragma unroll
      for (int i = 0; i < 16; ++i) {
        float av[4];
        *(float4*)&av[0] = *(const float4*)&Al[i][ty * 4];
#pragma unroll
        for (int m = 0; m < 3; ++m) {
          float w[8];
          *(float4*)&w[0] = *(const float4*)&Wl[m][i][tx * 4];
          *(float4*)&w[4] = *(const float4*)&Wl[m][i][64 + tx * 4];
#pragma unroll
          for (int j = 0; j < 4; ++j)
#pragma unroll
            for (int c = 0; c < 8; ++c) acc[m][j][c] += av[j] * w[c];
        }
      }
    }
  }

#pragma unroll
  for (int m = 0; m < 3; ++m) {
    float* Fm = F + (long)m * NN * IND;
    const float* bias = (m == 0) ? qb : (m == 1) ? kb : vb;
#pragma unroll
    for (int j = 0; j < 4; ++j) {
      int n = n0 + ty * 4 + j;
      if (n >= NN) continue;
      float* p0 = Fm + (long)n * IND + tx * 4;
      float4 v0 = make_float4(acc[m][j][0], acc[m][j][1], acc[m][j][2], acc[m][j][3]);
      float4 v1 = make_float4(acc[m][j][4], acc[m][j][5], acc[m][j][6], acc[m][j][7]);
      if (!first) {
        float4 o0 = *(float4*)p0, o1 = *(float4*)(p0 + 64);
        v0.x += o0.x; v0.y += o0.y; v0.z += o0.z; v0.w += o0.w;
        v1.x += o1.x; v1.y += o1.y; v1.z += o1.z; v1.w += o1.w;
      }
      if (last) {
        v0.x = fmaxf(v0.x + bias[tx * 4 + 0], 0.f);
        v0.y = fmaxf(v0.y + bias[tx * 4 + 1], 0.f);
        v0.z = fmaxf(v0.z + bias[tx * 4 + 2], 0.f);
        v0.w = fmaxf(v0.w + bias[tx * 4 + 3], 0.f);
        v1.x = fmaxf(v1.x + bias[64 + tx * 4 + 0], 0.f);
        v1.y = fmaxf(v1.y + bias[64 + tx * 4 + 1], 0.f);
        v1.z = fmaxf(v1.z + bias[64 + tx * 4 + 2], 0.f);
        v1.w = fmaxf(v1.w + bias[64 + tx * 4 + 3], 0.f);
      }
      *(float4*)p0 = v0;
      *(float4*)(p0 + 64) = v1;
    }
  }
}

// ---------------- per-node attention (no atomics, fused normalize) ----------
// wave per node d: lane holds elems 2l,2l+1. head = l/8; 8-lane shfl_xor reduce.
__global__ __launch_bounds__(256) void node_attn(const float* __restrict__ Q,
                                                 const float* __restrict__ K,
                                                 const float* __restrict__ V,
                                                 const int* __restrict__ rowptr,
                                                 const int* __restrict__ epk,
                                                 float* __restrict__ out) {
  int wid = (blockIdx.x * 256 + threadIdx.x) >> 6;
  int lane = threadIdx.x & 63;
  if (wid >= NN) return;
  float2 q = *(const float2*)(Q + (long)wid * IND + lane * 2);
  float accx = 0.f, accy = 0.f, zacc = 0.f;
  int r0 = rowptr[wid], r1 = rowptr[wid + 1];
  for (int base = r0; base < r1; base += 64) {
    int pe = (base + lane < r1) ? epk[base + lane] : 0;
    int cnt = min(64, r1 - base);
    for (int j = 0; j < cnt; ++j) {
      int s = __shfl(pe, j) & 0xFFFFF;
      float2 k = *(const float2*)(K + (long)s * IND + lane * 2);
      float2 v = *(const float2*)(V + (long)s * IND + lane * 2);
      float p = q.x * k.x + q.y * k.y;
      p += __shfl_xor(p, 1);
      p += __shfl_xor(p, 2);
      p += __shfl_xor(p, 4);
      float score = __expf(fminf(fmaxf(p * 0.25f, -10.f), 10.f));
      accx += score * v.x;
      accy += score * v.y;
      zacc += score;
    }
  }
  float inv = 1.f / (zacc + 1e-6f);
  *(float2*)(out + (long)wid * IND + lane * 2) = make_float2(accx * inv, accy * inv);
}

// ---------------- host ------------------------------------------------------
extern "C" void kernel_launch(void* const* d_in, const int* in_sizes, int n_in,
                              void* d_out, int out_size, void* d_ws, size_t ws_size,
                              hipStream_t stream) {
  const float* h  = (const float*)d_in[0];
  const float* Qw = (const float*)d_in[1];
  const float* Qc = (const float*)d_in[2];
  const float* Qb = (const float*)d_in[3];
  const float* Kw = (const float*)d_in[4];
  const float* Kc = (const float*)d_in[5];
  const float* Kb = (const float*)d_in[6];
  const float* Vw = (const float*)d_in[7];
  const float* Vc = (const float*)d_in[8];
  const float* Vb = (const float*)d_in[9];
  const int* src = (const int*)d_in[10];
  const int* dst = (const int*)d_in[11];
  const int* et  = (const int*)d_in[12];
  float* out = (float*)d_out;
  float* ws = (float*)d_ws;

  const long WSZ = (long)NR * IND * IND;       // 147456
  float* W3 = ws;                               // [3][R][IN][IN]
  float* F  = W3 + 3 * WSZ;                     // [3][N][IN]
  int* deg    = (int*)(F + 3L * NN * IND);      // [N]
  int* rowptr = deg + NN;                       // [N+1]
  int* cursor = rowptr + NN + 1;                // [N]
  int* bsum   = cursor + NN;                    // [NBLK]
  int* boff   = bsum + NBLK;                    // [NBLK]
  int* epk    = boff + NBLK;                    // [E]
  long int_total = (long)NN * 3 + 1 + 2 * NBLK + NE;
  int_total = (int_total + 3) & ~3L;            // 16B-align A
  float* A = (float*)(deg) + int_total;         // [C][N][IN]

  long usedf = 3 * WSZ + 3L * NN * IND + int_total;
  long availf = (long)(ws_size / 4) - usedf;
  long per_rel = (long)NN * IND;
  int C = (int)(availf / per_rel);
  if (C > NR) C = NR;
  if (C < 1) C = 1;

  hipMemsetAsync(deg, 0, (size_t)NN * 4, stream);

  combine_w<<<dim3(64, NR), 256, 0, stream>>>(Qw, Qc, W3);
  combine_w<<<dim3(64, NR), 256, 0, stream>>>(Kw, Kc, W3 + WSZ);
  combine_w<<<dim3(64, NR), 256, 0, stream>>>(Vw, Vc, W3 + 2 * WSZ);

  const int eb = (NE + 255) / 256;              // 3125
  hist_dst<<<eb, 256, 0, stream>>>(dst, deg);
  scan_p1<<<NBLK, 256, 0, stream>>>(deg, bsum);
  scan_p2<<<1, 256, 0, stream>>>(bsum, boff, rowptr);
  scan_p3<<<NBLK, 256, 0, stream>>>(deg, boff, rowptr, cursor);
  bucket_edges<<<eb, 256, 0, stream>>>(src, dst, et, cursor, epk);

  const int nwb = (NN * 64 + 255) / 256;        // 12500 blocks, wave per node
  const int gemm_blocks = (NN + 63) / 64;       // 782

  int first = 1;
  for (int rlo = 0; rlo < NR; rlo += C) {
    int rhi = rlo + C;
    if (rhi > NR) rhi = NR;
    int last = (rhi == NR) ? 1 : 0;
    conv_agg<<<nwb, 256, 0, stream>>>(h, rowptr, epk, A, rlo, rhi);
    gemm3<<<gemm_blocks, 256, 0, stream>>>(A, W3, F, Qb, Kb, Vb,
                                           rhi - rlo, rlo, first, last);
    first = 0;
  }

  node_attn<<<nwb, 256, 0, stream>>>(F, F + (long)NN * IND, F + 2L * NN * IND,
                                     rowptr, epk, out);
}

// Round 7
// 915.333 us; speedup vs baseline: 4.0127x; 1.2644x over previous
//
#include <hip/hip_runtime.h>

#define NN 50000
#define NE 800000
#define IND 128
#define NH 8
#define DH 16
#define NR 9
#define KTOT 1152     // NR*IND
#define NOUT 384      // 3*IND
#define OB_N 24       // NOUT/16
#define NBLK 196      // ceil(NN/256)

typedef __attribute__((ext_vector_type(8))) short bf16x8;
typedef __attribute__((ext_vector_type(4))) float f32x4;

__device__ __forceinline__ ushort f2bf(float x) {
  unsigned u = __float_as_uint(x);
  u += 0x7FFF + ((u >> 16) & 1);          // RNE
  return (ushort)(u >> 16);
}
__device__ __forceinline__ float bf2f(ushort h) {
  return __uint_as_float(((unsigned)h) << 16);
}

// ---- W precompute: frag-linear hi/lo bf16 for W[k = r*128+i][o = m*128+oc] -
// frag-linear: [kb][ob][lane][j], lane = ((k%32)/8)*16 + (o%16), j = k%8
__global__ __launch_bounds__(256) void make_w(const float* __restrict__ Qw, const float* __restrict__ Qc,
                                              const float* __restrict__ Kw, const float* __restrict__ Kc,
                                              const float* __restrict__ Vw, const float* __restrict__ Vc,
                                              ushort* __restrict__ Wh, ushort* __restrict__ Wl) {
  int t = blockIdx.x * 256 + threadIdx.x;     // 0..442367 (exact grid)
  int k = t / NOUT;
  int og = t % NOUT;
  int r = k >> 7, i = k & 127;
  int m = og >> 7, oc = og & 127;
  const float* basis = m == 0 ? Qw : m == 1 ? Kw : Vw;
  const float* comb  = m == 0 ? Qc : m == 1 ? Kc : Vc;
  float w = 0.f;
#pragma unroll
  for (int b = 0; b < NR; ++b)
    w += comb[r * NR + b] * basis[(long)b * IND * IND + i * IND + oc];
  ushort hi = f2bf(w);
  ushort lo = f2bf(w - bf2f(hi));
  long idx = ((long)(k >> 5) * OB_N + (og >> 4)) * 512
           + (((k >> 3) & 3) * 16 + (og & 15)) * 8 + (k & 7);
  Wh[idx] = hi;
  Wl[idx] = lo;
}

// ---------------- CSR build (proven in round 2) -----------------------------
__global__ __launch_bounds__(256) void hist_dst(const int* __restrict__ dst,
                                                int* __restrict__ deg) {
  int e = blockIdx.x * 256 + threadIdx.x;
  if (e < NE) atomicAdd(&deg[dst[e]], 1);
}

__global__ __launch_bounds__(256) void scan_p1(const int* __restrict__ deg,
                                               int* __restrict__ bsum) {
  __shared__ int sb[256];
  int t = threadIdx.x;
  int idx = blockIdx.x * 256 + t;
  int v = (idx < NN) ? deg[idx] : 0;
  sb[t] = v;
  __syncthreads();
  for (int off = 128; off > 0; off >>= 1) {
    if (t < off) sb[t] += sb[t + off];
    __syncthreads();
  }
  if (t == 0) bsum[blockIdx.x] = sb[0];
}

__global__ __launch_bounds__(256) void scan_p2(const int* __restrict__ bsum,
                                               int* __restrict__ boff,
                                               int* __restrict__ rowptr) {
  __shared__ int sb[256];
  int t = threadIdx.x;
  int v = (t < NBLK) ? bsum[t] : 0;
  sb[t] = v;
  __syncthreads();
  for (int off = 1; off < 256; off <<= 1) {
    int add = (t >= off) ? sb[t - off] : 0;
    __syncthreads();
    sb[t] += add;
    __syncthreads();
  }
  if (t < NBLK) boff[t] = sb[t] - v;   // exclusive
  if (t == 0) rowptr[NN] = NE;
}

__global__ __launch_bounds__(256) void scan_p3(const int* __restrict__ deg,
                                               const int* __restrict__ boff,
                                               int* __restrict__ rowptr,
                                               int* __restrict__ cursor) {
  __shared__ int sb[256];
  int t = threadIdx.x;
  int idx = blockIdx.x * 256 + t;
  int v = (idx < NN) ? deg[idx] : 0;
  sb[t] = v;
  __syncthreads();
  for (int off = 1; off < 256; off <<= 1) {
    int add = (t >= off) ? sb[t - off] : 0;
    __syncthreads();
    sb[t] += add;
    __syncthreads();
  }
  if (idx < NN) {
    int excl = sb[t] - v + boff[blockIdx.x];
    rowptr[idx] = excl;
    cursor[idx] = excl;
  }
}

__global__ __launch_bounds__(256) void bucket_edges(const int* __restrict__ src,
                                                    const int* __restrict__ dst,
                                                    const int* __restrict__ et,
                                                    int* __restrict__ cursor,
                                                    int* __restrict__ epk) {
  int e = blockIdx.x * 256 + threadIdx.x;
  if (e >= NE) return;
  int d = dst[e];
  int pos = atomicAdd(&cursor[d], 1);
  epk[pos] = src[e] | (et[e] << 20);   // src < 2^17, et < 16
}

// ---- per-node relational aggregation -> chunked hi/lo bf16 A ---------------
// A layout: [rr - rlo][n][128]
__global__ __launch_bounds__(256) void conv_agg(const float* __restrict__ x,
                                                const int* __restrict__ rowptr,
                                                const int* __restrict__ epk,
                                                ushort* __restrict__ Ah,
                                                ushort* __restrict__ Al,
                                                int rlo, int rhi) {
  int wid = (blockIdx.x * 256 + threadIdx.x) >> 6;
  int lane = threadIdx.x & 63;
  if (wid >= NN) return;
  float ax[NR], ay[NR];
#pragma unroll
  for (int rr = 0; rr < NR; ++rr) { ax[rr] = 0.f; ay[rr] = 0.f; }
  int r0 = rowptr[wid], r1 = rowptr[wid + 1];
  for (int base = r0; base < r1; base += 64) {
    int pe = (base + lane < r1) ? epk[base + lane] : 0;
    int cnt = min(64, r1 - base);
    for (int j = 0; j < cnt; ++j) {
      int p = __shfl(pe, j);
      int s = p & 0xFFFFF;
      int r = p >> 20;
      float2 xv = *(const float2*)(x + (long)s * IND + lane * 2);
#pragma unroll
      for (int rr = 0; rr < NR; ++rr)
        if (r == rr) { ax[rr] += xv.x; ay[rr] += xv.y; }
    }
  }
#pragma unroll
  for (int rr = 0; rr < NR; ++rr)
    if (rr >= rlo && rr < rhi) {
      ushort h0 = f2bf(ax[rr]);
      ushort l0 = f2bf(ax[rr] - bf2f(h0));
      ushort h1 = f2bf(ay[rr]);
      ushort l1 = f2bf(ay[rr] - bf2f(h1));
      long o = ((long)(rr - rlo) * NN + wid) * IND + lane * 2;
      *(unsigned*)(Ah + o) = (unsigned)h0 | ((unsigned)h1 << 16);
      *(unsigned*)(Al + o) = (unsigned)l0 | ((unsigned)l1 << 16);
    }
}

// ---- MFMA GEMM: F[3][N][128] (+)= A_chunk x W_chunk (+ bias, relu at last) -
// 512 thr = 8 waves (2M x 4N), block tile 64 rows x all 384 cols.
// 3-term bf16 split: ah*bl + al*bh + ah*bh ≈ fp32. No LDS, no barriers.
__global__ __launch_bounds__(512) void gemm_mfma(const ushort* __restrict__ Ah,
                                                 const ushort* __restrict__ Al,
                                                 const ushort* __restrict__ Wh,
                                                 const ushort* __restrict__ Wl,
                                                 const float* __restrict__ Qb,
                                                 const float* __restrict__ Kb,
                                                 const float* __restrict__ Vb,
                                                 float* __restrict__ F,
                                                 int nrel, int rlo, int first, int last) {
  const int tid = threadIdx.x;
  const int lane = tid & 63;
  const int wid = tid >> 6;
  const int wr = wid >> 2;            // 0..1
  const int wc = wid & 3;             // 0..3
  const int n0 = blockIdx.x * 64 + wr * 32;
  const int l15 = lane & 15;
  const int kg = lane >> 4;           // 0..3

  const int rowA = min(n0 + l15, NN - 1);
  const int rowB = min(n0 + 16 + l15, NN - 1);

  f32x4 acc[2][6];
#pragma unroll
  for (int mi = 0; mi < 2; ++mi)
#pragma unroll
    for (int ni = 0; ni < 6; ++ni) acc[mi][ni] = (f32x4){0.f, 0.f, 0.f, 0.f};

  for (int c = 0; c < nrel; ++c) {
    const long aoff0 = ((long)c * NN + rowA) * IND + kg * 8;
    const long aoff1 = ((long)c * NN + rowB) * IND + kg * 8;
    const int kbg0 = (rlo + c) * 4;     // global 32-K block base for this rel
#pragma unroll
    for (int kbl = 0; kbl < 4; ++kbl) {
      bf16x8 ah0 = *(const bf16x8*)(Ah + aoff0 + kbl * 32);
      bf16x8 ah1 = *(const bf16x8*)(Ah + aoff1 + kbl * 32);
      bf16x8 al0 = *(const bf16x8*)(Al + aoff0 + kbl * 32);
      bf16x8 al1 = *(const bf16x8*)(Al + aoff1 + kbl * 32);
#pragma unroll
      for (int ni = 0; ni < 6; ++ni) {
        const long boff = ((long)((kbg0 + kbl) * OB_N + wc * 6 + ni) * 64 + lane) * 8;
        bf16x8 bh = *(const bf16x8*)(Wh + boff);
        bf16x8 bl = *(const bf16x8*)(Wl + boff);
        acc[0][ni] = __builtin_amdgcn_mfma_f32_16x16x32_bf16(ah0, bl, acc[0][ni], 0, 0, 0);
        acc[0][ni] = __builtin_amdgcn_mfma_f32_16x16x32_bf16(al0, bh, acc[0][ni], 0, 0, 0);
        acc[0][ni] = __builtin_amdgcn_mfma_f32_16x16x32_bf16(ah0, bh, acc[0][ni], 0, 0, 0);
        acc[1][ni] = __builtin_amdgcn_mfma_f32_16x16x32_bf16(ah1, bl, acc[1][ni], 0, 0, 0);
        acc[1][ni] = __builtin_amdgcn_mfma_f32_16x16x32_bf16(al1, bh, acc[1][ni], 0, 0, 0);
        acc[1][ni] = __builtin_amdgcn_mfma_f32_16x16x32_bf16(ah1, bh, acc[1][ni], 0, 0, 0);
      }
    }
  }

#pragma unroll
  for (int mi = 0; mi < 2; ++mi) {
#pragma unroll
    for (int ni = 0; ni < 6; ++ni) {
      int og = wc * 96 + ni * 16 + l15;          // 0..383, C/D col = lane&15
      int m = og >> 7, oc = og & 127;
      float b = (m == 0 ? Qb : m == 1 ? Kb : Vb)[oc];
      float* Fm = F + (long)m * NN * IND;
#pragma unroll
      for (int reg = 0; reg < 4; ++reg) {
        int n = n0 + mi * 16 + kg * 4 + reg;     // C/D row = (lane>>4)*4+reg
        if (n < NN) {
          long fo = (long)n * IND + oc;
          float v = acc[mi][ni][reg];
          if (!first) v += Fm[fo];
          if (last) { v += b; v = v > 0.f ? v : 0.f; }
          Fm[fo] = v;
        }
      }
    }
  }
}

// ---- per-node attention (no atomics, fused normalize; proven round 2) ------
__global__ __launch_bounds__(256) void node_attn(const float* __restrict__ Q,
                                                 const float* __restrict__ K,
                                                 const float* __restrict__ V,
                                                 const int* __restrict__ rowptr,
                                                 const int* __restrict__ epk,
                                                 float* __restrict__ out) {
  int wid = (blockIdx.x * 256 + threadIdx.x) >> 6;
  int lane = threadIdx.x & 63;
  if (wid >= NN) return;
  float2 q = *(const float2*)(Q + (long)wid * IND + lane * 2);
  float accx = 0.f, accy = 0.f, zacc = 0.f;
  int r0 = rowptr[wid], r1 = rowptr[wid + 1];
  for (int base = r0; base < r1; base += 64) {
    int pe = (base + lane < r1) ? epk[base + lane] : 0;
    int cnt = min(64, r1 - base);
    for (int j = 0; j < cnt; ++j) {
      int s = __shfl(pe, j) & 0xFFFFF;
      float2 k = *(const float2*)(K + (long)s * IND + lane * 2);
      float2 v = *(const float2*)(V + (long)s * IND + lane * 2);
      float p = q.x * k.x + q.y * k.y;
      p += __shfl_xor(p, 1);
      p += __shfl_xor(p, 2);
      p += __shfl_xor(p, 4);
      float score = __expf(fminf(fmaxf(p * 0.25f, -10.f), 10.f));
      accx += score * v.x;
      accy += score * v.y;
      zacc += score;
    }
  }
  float inv = 1.f / (zacc + 1e-6f);
  *(float2*)(out + (long)wid * IND + lane * 2) = make_float2(accx * inv, accy * inv);
}

// ---------------- host ------------------------------------------------------
extern "C" void kernel_launch(void* const* d_in, const int* in_sizes, int n_in,
                              void* d_out, int out_size, void* d_ws, size_t ws_size,
                              hipStream_t stream) {
  const float* h  = (const float*)d_in[0];
  const float* Qw = (const float*)d_in[1];
  const float* Qc = (const float*)d_in[2];
  const float* Qb = (const float*)d_in[3];
  const float* Kw = (const float*)d_in[4];
  const float* Kc = (const float*)d_in[5];
  const float* Kb = (const float*)d_in[6];
  const float* Vw = (const float*)d_in[7];
  const float* Vc = (const float*)d_in[8];
  const float* Vb = (const float*)d_in[9];
  const int* src = (const int*)d_in[10];
  const int* dst = (const int*)d_in[11];
  const int* et  = (const int*)d_in[12];
  float* out = (float*)d_out;

  // ---- workspace layout: all in d_ws, fixed part 82.37 MB; peak C=9 needs
  // 312.77 MB < round-2-proven ws_size >= 316.3 MB.
  char* p = (char*)d_ws;
  ushort* Wh = (ushort*)p;  p += (long)KTOT * NOUT * 2;    // 884,736 B
  ushort* Wl = (ushort*)p;  p += (long)KTOT * NOUT * 2;    // 884,736 B
  float* F   = (float*)p;   p += 3L * NN * IND * 4;        // 76,800,000 B
  int* deg    = (int*)p;
  int* rowptr = deg + NN;
  int* cursor = rowptr + NN + 1;
  int* bsum   = cursor + NN;
  int* boff   = bsum + NBLK;
  int* epk    = boff + NBLK;
  long intbytes = (((long)(3 * NN + 1 + 2 * NBLK + NE)) * 4 + 15) & ~15L;
  p += intbytes;
  ushort* Ah = (ushort*)p;
  long fixed = (long)(p - (char*)d_ws);
  long per_rel = 2L * NN * IND * 2;                         // Ah+Al, 25.6 MB/rel
  int C = (int)(((long)ws_size - fixed) / per_rel);
  if (C > NR) C = NR;
  if (C < 1) C = 1;
  ushort* Al = Ah + (long)C * NN * IND;

  hipMemsetAsync(deg, 0, (size_t)NN * 4, stream);

  make_w<<<(KTOT * NOUT) / 256, 256, 0, stream>>>(Qw, Qc, Kw, Kc, Vw, Vc, Wh, Wl);

  const int eb = (NE + 255) / 256;              // 3125
  hist_dst<<<eb, 256, 0, stream>>>(dst, deg);
  scan_p1<<<NBLK, 256, 0, stream>>>(deg, bsum);
  scan_p2<<<1, 256, 0, stream>>>(bsum, boff, rowptr);
  scan_p3<<<NBLK, 256, 0, stream>>>(deg, boff, rowptr, cursor);
  bucket_edges<<<eb, 256, 0, stream>>>(src, dst, et, cursor, epk);

  const int nwb = (NN * 64 + 255) / 256;        // 12500
  const int gb  = (NN + 63) / 64;               // 782

  int first = 1;
  for (int rlo = 0; rlo < NR; rlo += C) {
    int rhi = rlo + C;
    if (rhi > NR) rhi = NR;
    conv_agg<<<nwb, 256, 0, stream>>>(h, rowptr, epk, Ah, Al, rlo, rhi);
    gemm_mfma<<<gb, 512, 0, stream>>>(Ah, Al, Wh, Wl, Qb, Kb, Vb, F,
                                      rhi - rlo, rlo, first, (rhi == NR) ? 1 : 0);
    first = 0;
  }

  node_attn<<<nwb, 256, 0, stream>>>(F, F + (long)NN * IND, F + 2L * NN * IND,
                                     rowptr, epk, out);
}

// Round 8
// 764.570 us; speedup vs baseline: 4.8040x; 1.1972x over previous
//
#include <hip/hip_runtime.h>

#define NN 50000
#define NE 800000
#define IND 128
#define NH 8
#define DH 16
#define NR 9
#define KTOT 1152     // NR*IND
#define NOUT 384      // 3*IND
#define OB_N 24       // NOUT/16
#define NBLK 196      // ceil(NN/256)

typedef __attribute__((ext_vector_type(8))) short bf16x8;
typedef __attribute__((ext_vector_type(4))) float f32x4;

__device__ __forceinline__ ushort f2bf(float x) {
  unsigned u = __float_as_uint(x);
  u += 0x7FFF + ((u >> 16) & 1);          // RNE
  return (ushort)(u >> 16);
}
__device__ __forceinline__ float bf2f(ushort h) {
  return __uint_as_float(((unsigned)h) << 16);
}

// ---- W precompute: frag-linear hi/lo bf16 for W[k = r*128+i][o = m*128+oc] -
// frag-linear: [kb][ob][lane][j], lane = ((k%32)/8)*16 + (o%16), j = k%8
__global__ __launch_bounds__(256) void make_w(const float* __restrict__ Qw, const float* __restrict__ Qc,
                                              const float* __restrict__ Kw, const float* __restrict__ Kc,
                                              const float* __restrict__ Vw, const float* __restrict__ Vc,
                                              ushort* __restrict__ Wh, ushort* __restrict__ Wl) {
  int t = blockIdx.x * 256 + threadIdx.x;     // 0..442367 (exact grid)
  int k = t / NOUT;
  int og = t % NOUT;
  int r = k >> 7, i = k & 127;
  int m = og >> 7, oc = og & 127;
  const float* basis = m == 0 ? Qw : m == 1 ? Kw : Vw;
  const float* comb  = m == 0 ? Qc : m == 1 ? Kc : Vc;
  float w = 0.f;
#pragma unroll
  for (int b = 0; b < NR; ++b)
    w += comb[r * NR + b] * basis[(long)b * IND * IND + i * IND + oc];
  ushort hi = f2bf(w);
  ushort lo = f2bf(w - bf2f(hi));
  long idx = ((long)(k >> 5) * OB_N + (og >> 4)) * 512
           + (((k >> 3) & 3) * 16 + (og & 15)) * 8 + (k & 7);
  Wh[idx] = hi;
  Wl[idx] = lo;
}

// ---------------- CSR build (proven in round 2) -----------------------------
__global__ __launch_bounds__(256) void hist_dst(const int* __restrict__ dst,
                                                int* __restrict__ deg) {
  int e = blockIdx.x * 256 + threadIdx.x;
  if (e < NE) atomicAdd(&deg[dst[e]], 1);
}

__global__ __launch_bounds__(256) void scan_p1(const int* __restrict__ deg,
                                               int* __restrict__ bsum) {
  __shared__ int sb[256];
  int t = threadIdx.x;
  int idx = blockIdx.x * 256 + t;
  int v = (idx < NN) ? deg[idx] : 0;
  sb[t] = v;
  __syncthreads();
  for (int off = 128; off > 0; off >>= 1) {
    if (t < off) sb[t] += sb[t + off];
    __syncthreads();
  }
  if (t == 0) bsum[blockIdx.x] = sb[0];
}

__global__ __launch_bounds__(256) void scan_p2(const int* __restrict__ bsum,
                                               int* __restrict__ boff,
                                               int* __restrict__ rowptr) {
  __shared__ int sb[256];
  int t = threadIdx.x;
  int v = (t < NBLK) ? bsum[t] : 0;
  sb[t] = v;
  __syncthreads();
  for (int off = 1; off < 256; off <<= 1) {
    int add = (t >= off) ? sb[t - off] : 0;
    __syncthreads();
    sb[t] += add;
    __syncthreads();
  }
  if (t < NBLK) boff[t] = sb[t] - v;   // exclusive
  if (t == 0) rowptr[NN] = NE;
}

__global__ __launch_bounds__(256) void scan_p3(const int* __restrict__ deg,
                                               const int* __restrict__ boff,
                                               int* __restrict__ rowptr,
                                               int* __restrict__ cursor) {
  __shared__ int sb[256];
  int t = threadIdx.x;
  int idx = blockIdx.x * 256 + t;
  int v = (idx < NN) ? deg[idx] : 0;
  sb[t] = v;
  __syncthreads();
  for (int off = 1; off < 256; off <<= 1) {
    int add = (t >= off) ? sb[t - off] : 0;
    __syncthreads();
    sb[t] += add;
    __syncthreads();
  }
  if (idx < NN) {
    int excl = sb[t] - v + boff[blockIdx.x];
    rowptr[idx] = excl;
    cursor[idx] = excl;
  }
}

__global__ __launch_bounds__(256) void bucket_edges(const int* __restrict__ src,
                                                    const int* __restrict__ dst,
                                                    const int* __restrict__ et,
                                                    int* __restrict__ cursor,
                                                    int* __restrict__ epk) {
  int e = blockIdx.x * 256 + threadIdx.x;
  if (e >= NE) return;
  int d = dst[e];
  int pos = atomicAdd(&cursor[d], 1);
  epk[pos] = src[e] | (et[e] << 20);   // src < 2^17, et < 16
}

// ---- per-node relational aggregation -> chunked hi/lo bf16 A ---------------
// A layout: [rr - rlo][n][128]
__global__ __launch_bounds__(256) void conv_agg(const float* __restrict__ x,
                                                const int* __restrict__ rowptr,
                                                const int* __restrict__ epk,
                                                ushort* __restrict__ Ah,
                                                ushort* __restrict__ Al,
                                                int rlo, int rhi) {
  int wid = (blockIdx.x * 256 + threadIdx.x) >> 6;
  int lane = threadIdx.x & 63;
  if (wid >= NN) return;
  float ax[NR], ay[NR];
#pragma unroll
  for (int rr = 0; rr < NR; ++rr) { ax[rr] = 0.f; ay[rr] = 0.f; }
  int r0 = rowptr[wid], r1 = rowptr[wid + 1];
  for (int base = r0; base < r1; base += 64) {
    int pe = (base + lane < r1) ? epk[base + lane] : 0;
    int cnt = min(64, r1 - base);
    for (int j = 0; j < cnt; ++j) {
      int p = __shfl(pe, j);
      int s = p & 0xFFFFF;
      int r = p >> 20;
      float2 xv = *(const float2*)(x + (long)s * IND + lane * 2);
#pragma unroll
      for (int rr = 0; rr < NR; ++rr)
        if (r == rr) { ax[rr] += xv.x; ay[rr] += xv.y; }
    }
  }
#pragma unroll
  for (int rr = 0; rr < NR; ++rr)
    if (rr >= rlo && rr < rhi) {
      ushort h0 = f2bf(ax[rr]);
      ushort l0 = f2bf(ax[rr] - bf2f(h0));
      ushort h1 = f2bf(ay[rr]);
      ushort l1 = f2bf(ay[rr] - bf2f(h1));
      long o = ((long)(rr - rlo) * NN + wid) * IND + lane * 2;
      *(unsigned*)(Ah + o) = (unsigned)h0 | ((unsigned)h1 << 16);
      *(unsigned*)(Al + o) = (unsigned)l0 | ((unsigned)l1 << 16);
    }
}

// ---- MFMA GEMM v2: software-pipelined, latency-hiding ----------------------
// 512 thr = 8 waves (2wr x 4wc); wave tile 64 x 96 (acc[4][6]); block 128x384.
// A double-buffered in registers (HBM latency hidden under 144-MFMA block),
// W single-buffered (L2-resident). 3-term bf16 split. No LDS, no barriers.
__global__ __launch_bounds__(512) void gemm_mfma(const ushort* __restrict__ Ah,
                                                 const ushort* __restrict__ Al,
                                                 const ushort* __restrict__ Wh,
                                                 const ushort* __restrict__ Wl,
                                                 const float* __restrict__ Qb,
                                                 const float* __restrict__ Kb,
                                                 const float* __restrict__ Vb,
                                                 float* __restrict__ F,
                                                 int nrel, int rlo, int first, int last) {
  const int tid = threadIdx.x;
  const int lane = tid & 63;
  const int wid = tid >> 6;
  const int wr = wid >> 2;            // 0..1
  const int wc = wid & 3;             // 0..3
  const int n0 = blockIdx.x * 128 + wr * 64;
  const int l15 = lane & 15;
  const int kg = lane >> 4;           // 0..3
  const int kgofs = kg * 8;

  long rowOff[4];
#pragma unroll
  for (int mi = 0; mi < 4; ++mi)
    rowOff[mi] = (long)min(n0 + mi * 16 + l15, NN - 1) * IND;

  const int nsteps = nrel * 4;        // multiple of 4, loop unrolled by 2

  f32x4 acc[4][6];
#pragma unroll
  for (int mi = 0; mi < 4; ++mi)
#pragma unroll
    for (int ni = 0; ni < 6; ++ni) acc[mi][ni] = (f32x4){0.f, 0.f, 0.f, 0.f};

  bf16x8 a0[8], a1[8], w[12];

  auto LOADA = [&](bf16x8* A, int s) {
    const long ab = ((long)(s >> 2) * NN) * IND + ((s & 3) * 32 + kgofs);
#pragma unroll
    for (int mi = 0; mi < 4; ++mi) {
      A[mi]     = *(const bf16x8*)(Ah + ab + rowOff[mi]);
      A[4 + mi] = *(const bf16x8*)(Al + ab + rowOff[mi]);
    }
  };
  auto LOADW = [&](bf16x8* W, int s) {
    const long wb = (((long)(rlo * 4 + s) * OB_N + wc * 6) * 64 + lane) * 8;
#pragma unroll
    for (int ni = 0; ni < 6; ++ni) {
      W[ni]     = *(const bf16x8*)(Wh + wb + ni * 512);
      W[6 + ni] = *(const bf16x8*)(Wl + wb + ni * 512);
    }
  };
  auto DOMFMA = [&](bf16x8* A, bf16x8* W) {
#pragma unroll
    for (int ni = 0; ni < 6; ++ni)
#pragma unroll
      for (int mi = 0; mi < 4; ++mi) {
        acc[mi][ni] = __builtin_amdgcn_mfma_f32_16x16x32_bf16(A[mi],     W[6 + ni], acc[mi][ni], 0, 0, 0);
        acc[mi][ni] = __builtin_amdgcn_mfma_f32_16x16x32_bf16(A[4 + mi], W[ni],     acc[mi][ni], 0, 0, 0);
        acc[mi][ni] = __builtin_amdgcn_mfma_f32_16x16x32_bf16(A[mi],     W[ni],     acc[mi][ni], 0, 0, 0);
      }
  };

  LOADA(a0, 0);
  LOADW(w, 0);
  for (int s = 0; s < nsteps; s += 2) {
    LOADA(a1, s + 1);                  // prefetch next A (deep: used after 144 MFMAs)
    DOMFMA(a0, w);                     // step s
    LOADW(w, s + 1);
    if (s + 2 < nsteps) LOADA(a0, s + 2);
    DOMFMA(a1, w);                     // step s+1
    if (s + 2 < nsteps) LOADW(w, s + 2);
  }

#pragma unroll
  for (int mi = 0; mi < 4; ++mi) {
#pragma unroll
    for (int ni = 0; ni < 6; ++ni) {
      int og = wc * 96 + ni * 16 + l15;          // 0..383, C/D col = lane&15
      int m = og >> 7, oc = og & 127;
      float b = (m == 0 ? Qb : m == 1 ? Kb : Vb)[oc];
      float* Fm = F + (long)m * NN * IND;
#pragma unroll
      for (int reg = 0; reg < 4; ++reg) {
        int n = n0 + mi * 16 + kg * 4 + reg;     // C/D row = (lane>>4)*4+reg
        if (n < NN) {
          long fo = (long)n * IND + oc;
          float v = acc[mi][ni][reg];
          if (!first) v += Fm[fo];
          if (last) { v += b; v = v > 0.f ? v : 0.f; }
          Fm[fo] = v;
        }
      }
    }
  }
}

// ---- per-node attention (no atomics, fused normalize; proven round 2) ------
__global__ __launch_bounds__(256) void node_attn(const float* __restrict__ Q,
                                                 const float* __restrict__ K,
                                                 const float* __restrict__ V,
                                                 const int* __restrict__ rowptr,
                                                 const int* __restrict__ epk,
                                                 float* __restrict__ out) {
  int wid = (blockIdx.x * 256 + threadIdx.x) >> 6;
  int lane = threadIdx.x & 63;
  if (wid >= NN) return;
  float2 q = *(const float2*)(Q + (long)wid * IND + lane * 2);
  float accx = 0.f, accy = 0.f, zacc = 0.f;
  int r0 = rowptr[wid], r1 = rowptr[wid + 1];
  for (int base = r0; base < r1; base += 64) {
    int pe = (base + lane < r1) ? epk[base + lane] : 0;
    int cnt = min(64, r1 - base);
    for (int j = 0; j < cnt; ++j) {
      int s = __shfl(pe, j) & 0xFFFFF;
      float2 k = *(const float2*)(K + (long)s * IND + lane * 2);
      float2 v = *(const float2*)(V + (long)s * IND + lane * 2);
      float p = q.x * k.x + q.y * k.y;
      p += __shfl_xor(p, 1);
      p += __shfl_xor(p, 2);
      p += __shfl_xor(p, 4);
      float score = __expf(fminf(fmaxf(p * 0.25f, -10.f), 10.f));
      accx += score * v.x;
      accy += score * v.y;
      zacc += score;
    }
  }
  float inv = 1.f / (zacc + 1e-6f);
  *(float2*)(out + (long)wid * IND + lane * 2) = make_float2(accx * inv, accy * inv);
}

// ---------------- host ------------------------------------------------------
extern "C" void kernel_launch(void* const* d_in, const int* in_sizes, int n_in,
                              void* d_out, int out_size, void* d_ws, size_t ws_size,
                              hipStream_t stream) {
  const float* h  = (const float*)d_in[0];
  const float* Qw = (const float*)d_in[1];
  const float* Qc = (const float*)d_in[2];
  const float* Qb = (const float*)d_in[3];
  const float* Kw = (const float*)d_in[4];
  const float* Kc = (const float*)d_in[5];
  const float* Kb = (const float*)d_in[6];
  const float* Vw = (const float*)d_in[7];
  const float* Vc = (const float*)d_in[8];
  const float* Vb = (const float*)d_in[9];
  const int* src = (const int*)d_in[10];
  const int* dst = (const int*)d_in[11];
  const int* et  = (const int*)d_in[12];
  float* out = (float*)d_out;

  // ---- workspace layout: all in d_ws, fixed part 82.37 MB; peak C=9 needs
  // 312.77 MB < round-2-proven ws_size >= 316.3 MB.
  char* p = (char*)d_ws;
  ushort* Wh = (ushort*)p;  p += (long)KTOT * NOUT * 2;    // 884,736 B
  ushort* Wl = (ushort*)p;  p += (long)KTOT * NOUT * 2;    // 884,736 B
  float* F   = (float*)p;   p += 3L * NN * IND * 4;        // 76,800,000 B
  int* deg    = (int*)p;
  int* rowptr = deg + NN;
  int* cursor = rowptr + NN + 1;
  int* bsum   = cursor + NN;
  int* boff   = bsum + NBLK;
  int* epk    = boff + NBLK;
  long intbytes = (((long)(3 * NN + 1 + 2 * NBLK + NE)) * 4 + 15) & ~15L;
  p += intbytes;
  ushort* Ah = (ushort*)p;
  long fixed = (long)(p - (char*)d_ws);
  long per_rel = 2L * NN * IND * 2;                         // Ah+Al, 25.6 MB/rel
  int C = (int)(((long)ws_size - fixed) / per_rel);
  if (C > NR) C = NR;
  if (C < 1) C = 1;
  ushort* Al = Ah + (long)C * NN * IND;

  hipMemsetAsync(deg, 0, (size_t)NN * 4, stream);

  make_w<<<(KTOT * NOUT) / 256, 256, 0, stream>>>(Qw, Qc, Kw, Kc, Vw, Vc, Wh, Wl);

  const int eb = (NE + 255) / 256;              // 3125
  hist_dst<<<eb, 256, 0, stream>>>(dst, deg);
  scan_p1<<<NBLK, 256, 0, stream>>>(deg, bsum);
  scan_p2<<<1, 256, 0, stream>>>(bsum, boff, rowptr);
  scan_p3<<<NBLK, 256, 0, stream>>>(deg, boff, rowptr, cursor);
  bucket_edges<<<eb, 256, 0, stream>>>(src, dst, et, cursor, epk);

  const int nwb = (NN * 64 + 255) / 256;        // 12500
  const int gb  = (NN + 127) / 128;             // 391

  int first = 1;
  for (int rlo = 0; rlo < NR; rlo += C) {
    int rhi = rlo + C;
    if (rhi > NR) rhi = NR;
    conv_agg<<<nwb, 256, 0, stream>>>(h, rowptr, epk, Ah, Al, rlo, rhi);
    gemm_mfma<<<gb, 512, 0, stream>>>(Ah, Al, Wh, Wl, Qb, Kb, Vb, F,
                                      rhi - rlo, rlo, first, (rhi == NR) ? 1 : 0);
    first = 0;
  }

  node_attn<<<nwb, 256, 0, stream>>>(F, F + (long)NN * IND, F + 2L * NN * IND,
                                     rowptr, epk, out);
}